// Round 2
// baseline (717.835 us; speedup 1.0000x reference)
//
#include <hip/hip_runtime.h>
#include <hip/hip_bf16.h>
#include <cmath>

// ALiBi windowed-causal attention block, MI355X.
// R2: GEMMs moved to bf16x3 split MFMA (hi/lo decomposition, 3 mfma terms),
//     conversion fused into LDS staging with XOR-swizzled tiles.
//     Attention kernel unchanged (fp32 VALU, windowed online softmax).
// B=2, N=2048, C=1024, H=16, D=64, WINDOW=256, causal.
#define B_ 2
#define N_ 2048
#define C_ 1024
#define H_ 16
#define D_ 64
#define BHND (B_*H_*N_*D_)   // 4,194,304 elems per q/k/v tensor

typedef __attribute__((ext_vector_type(8))) short  bf16x8;   // 4 VGPR MFMA frag
typedef __attribute__((ext_vector_type(4))) float  f32x4;    // 4 VGPR acc frag
typedef __attribute__((ext_vector_type(4))) unsigned int uint4v;

// pack bf16(x0),bf16(x1) (truncation) into one u32: lo16=x0.top16, hi16=x1.top16
__device__ __forceinline__ unsigned pack_hi2(float x0, float x1) {
  // v_perm_b32: sel byte values 0-3 pick from src1, 4-7 from src0
  return __builtin_amdgcn_perm(__float_as_uint(x1), __float_as_uint(x0), 0x07060302u);
}
__device__ __forceinline__ float trunc16(float x) {
  return __uint_as_float(__float_as_uint(x) & 0xFFFF0000u);
}
// 8 fp32 (2 float4) -> 4+4 packed bf16 words (hi, lo parts)
__device__ __forceinline__ void cvt8(const float4 u, const float4 v,
                                     uint4v& hi, uint4v& lo) {
  hi.x = pack_hi2(u.x, u.y); hi.y = pack_hi2(u.z, u.w);
  hi.z = pack_hi2(v.x, v.y); hi.w = pack_hi2(v.z, v.w);
  float l0 = u.x - trunc16(u.x), l1 = u.y - trunc16(u.y);
  float l2 = u.z - trunc16(u.z), l3 = u.w - trunc16(u.w);
  float l4 = v.x - trunc16(v.x), l5 = v.y - trunc16(v.y);
  float l6 = v.z - trunc16(v.z), l7 = v.w - trunc16(v.w);
  lo.x = pack_hi2(l0, l1); lo.y = pack_hi2(l2, l3);
  lo.z = pack_hi2(l4, l5); lo.w = pack_hi2(l6, l7);
}
// byte offset of (row, k-elem) in a [128][64]-bf16 tile, XOR-swizzled so a
// 16-row column slice of ds_read_b128 spreads over all 32 banks.
__device__ __forceinline__ int swz(int row, int kelem) {
  return ((row << 7) + (kelem << 1)) ^ ((row & 7) << 4);
}

// ---------------------------------------------------------------------------
// out = A @ Bw^T + bias via bf16x3 MFMA. A:[M,K] fp32 row-major, Bw:[Nc,K].
// MODE 0: direct store. MODE 1: scatter cols into qkv [3][B*H][N][D].
// 128x128 tile, BK=64, 256 threads = 4 waves (2x2), 64x64 out per wave.
// ---------------------------------------------------------------------------
template<int MODE>
__global__ __launch_bounds__(256, 2)
void gemm3_nt(const float* __restrict__ A, const float* __restrict__ Bw,
              const float* __restrict__ bias, float* __restrict__ Cd,
              int Ncols, int K)
{
  __shared__ char smem[65536];
  char* Ah = smem;          char* Al = smem + 16384;
  char* Bh = smem + 32768;  char* Bl = smem + 49152;

  const int t    = threadIdx.x;
  const int lane = t & 63;
  const int w    = t >> 6;
  const int wm   = w >> 1, wn = w & 1;      // wave grid 2x2
  const int mb   = blockIdx.x, nb = blockIdx.y;

  // staging assignment: thread -> (row, 32-float k-half)
  const int srow = t >> 1;
  const int skh  = (t & 1) * 32;
  const float* Ag = A  + (size_t)(mb*128 + srow)*K + skh;
  const float* Bg = Bw + (size_t)(nb*128 + srow)*K + skh;

  f32x4 acc[4][4];
  #pragma unroll
  for (int m = 0; m < 4; ++m)
    #pragma unroll
    for (int n = 0; n < 4; ++n) acc[m][n] = (f32x4)0.f;

  float4 fa[8], fb[8];
  {
    const float4* ap = (const float4*)Ag;
    const float4* bp = (const float4*)Bg;
    #pragma unroll
    for (int i = 0; i < 8; ++i) { fa[i] = ap[i]; fb[i] = bp[i]; }
  }

  const int fr = lane & 15;       // fragment row/col within 16
  const int fg = lane >> 4;       // k-group 0..3
  const int nkt = K / 64;

  for (int kt = 0; kt < nkt; ++kt) {
    __syncthreads();              // prev compute's ds_reads done
    #pragma unroll
    for (int c = 0; c < 4; ++c) { // convert 8 elems at a time, swizzled write
      uint4v hi, lo;
      const int off = swz(srow, skh + c*8);
      cvt8(fa[2*c], fa[2*c+1], hi, lo);
      *(uint4v*)(Ah + off) = hi;  *(uint4v*)(Al + off) = lo;
      cvt8(fb[2*c], fb[2*c+1], hi, lo);
      *(uint4v*)(Bh + off) = hi;  *(uint4v*)(Bl + off) = lo;
    }
    __syncthreads();              // tiles visible to all waves
    if (kt + 1 < nkt) {           // prefetch next K-step (hides under MFMA)
      const float4* ap = (const float4*)(Ag + (kt+1)*64);
      const float4* bp = (const float4*)(Bg + (kt+1)*64);
      #pragma unroll
      for (int i = 0; i < 8; ++i) { fa[i] = ap[i]; fb[i] = bp[i]; }
    }
    #pragma unroll
    for (int ks = 0; ks < 2; ++ks) {   // two K=32 slices
      const int ke = ks*32 + fg*8;
      bf16x8 ah[4], al[4];
      #pragma unroll
      for (int m = 0; m < 4; ++m) {
        const int off = swz(wm*64 + m*16 + fr, ke);
        ah[m] = *(const bf16x8*)(Ah + off);
        al[m] = *(const bf16x8*)(Al + off);
      }
      #pragma unroll
      for (int n = 0; n < 4; ++n) {
        const int off = swz(wn*64 + n*16 + fr, ke);
        const bf16x8 bh = *(const bf16x8*)(Bh + off);
        const bf16x8 bl = *(const bf16x8*)(Bl + off);
        #pragma unroll
        for (int m = 0; m < 4; ++m) {
          acc[m][n] = __builtin_amdgcn_mfma_f32_16x16x32_bf16(ah[m], bh, acc[m][n], 0, 0, 0);
          acc[m][n] = __builtin_amdgcn_mfma_f32_16x16x32_bf16(al[m], bh, acc[m][n], 0, 0, 0);
          acc[m][n] = __builtin_amdgcn_mfma_f32_16x16x32_bf16(ah[m], bl, acc[m][n], 0, 0, 0);
        }
      }
    }
  }

  // epilogue: C/D frag layout col=lane&15, row=(lane>>4)*4+reg (m89)
  #pragma unroll
  for (int n = 0; n < 4; ++n) {
    const int col = nb*128 + wn*64 + n*16 + fr;
    const float bb = bias[col];
    int which = 0, hh = 0, dd = 0;
    if (MODE == 1) { which = col >> 10; hh = (col >> 6) & 15; dd = col & 63; }
    #pragma unroll
    for (int m = 0; m < 4; ++m) {
      const int row0 = mb*128 + wm*64 + m*16 + fg*4;
      #pragma unroll
      for (int j = 0; j < 4; ++j) {
        const int row = row0 + j;
        const float val = acc[m][n][j] + bb;
        if (MODE == 0) {
          Cd[(size_t)row*Ncols + col] = val;
        } else {
          const int b = row >> 11, i = row & 2047;
          Cd[(size_t)which*BHND + (((size_t)(b*H_ + hh))*N_ + i)*D_ + dd] = val;
        }
      }
    }
  }
}

// ---------------------------------------------------------------------------
// Windowed causal ALiBi attention (fp32). One wave per 64-query tile of one
// (b,h); query-per-lane, online softmax; j wave-uniform -> broadcast loads.
// ---------------------------------------------------------------------------
__global__ __launch_bounds__(64)
void attn_win(const float* __restrict__ qkv, float* __restrict__ attn_out)
{
  const int lane = threadIdx.x;
  const int qt   = blockIdx.x & 31;
  const int bh   = blockIdx.x >> 5;
  const int h    = bh & 15;
  const int i    = qt*64 + lane;

  const float* qrow  = qkv + ((size_t)bh*N_ + i)*D_;
  const float* kbase = qkv + (size_t)BHND + (size_t)bh*N_*D_;
  const float* vbase = kbase + (size_t)BHND;

  float q[64];
  #pragma unroll
  for (int d4 = 0; d4 < 16; ++d4) {
    float4 qv = ((const float4*)qrow)[d4];
    q[d4*4+0] = qv.x; q[d4*4+1] = qv.y; q[d4*4+2] = qv.z; q[d4*4+3] = qv.w;
  }
  float o[64];
  #pragma unroll
  for (int d = 0; d < 64; ++d) o[d] = 0.f;
  float mrun = -1e30f, lrun = 0.f;
  const float slope = exp2f(-0.5f * (float)(h + 1));

  const int jlo = max(0, qt*64 - 255);
  const int jhi = qt*64 + 63;
  for (int j = jlo; j <= jhi; ++j) {
    const float4* krow = (const float4*)(kbase + (size_t)j*D_);
    float s = 0.f;
    #pragma unroll
    for (int d4 = 0; d4 < 16; ++d4) {
      float4 kv = krow[d4];
      s = fmaf(q[d4*4+0], kv.x, s);
      s = fmaf(q[d4*4+1], kv.y, s);
      s = fmaf(q[d4*4+2], kv.z, s);
      s = fmaf(q[d4*4+3], kv.w, s);
    }
    s = s*0.125f + slope*(float)(j - i);       // SCALE + alibi (rel = j-i <= 0)
    if (j <= i && j >= i - 255) {              // causal + sliding window
      const float mn   = fmaxf(mrun, s);
      const float corr = __expf(mrun - mn);
      const float p    = __expf(s - mn);
      lrun = lrun*corr + p;
      mrun = mn;
      const float4* vrow = (const float4*)(vbase + (size_t)j*D_);
      #pragma unroll
      for (int d4 = 0; d4 < 16; ++d4) {
        float4 vv = vrow[d4];
        o[d4*4+0] = fmaf(p, vv.x, o[d4*4+0]*corr);
        o[d4*4+1] = fmaf(p, vv.y, o[d4*4+1]*corr);
        o[d4*4+2] = fmaf(p, vv.z, o[d4*4+2]*corr);
        o[d4*4+3] = fmaf(p, vv.w, o[d4*4+3]*corr);
      }
    }
  }

  const float inv = 1.f / lrun;
  const int b = bh >> 4;
  float* dst = attn_out + ((size_t)b*N_ + i)*C_ + h*D_;   // [B,N,H*D]
  #pragma unroll
  for (int d4 = 0; d4 < 16; ++d4) {
    float4 ov;
    ov.x = o[d4*4+0]*inv; ov.y = o[d4*4+1]*inv;
    ov.z = o[d4*4+2]*inv; ov.w = o[d4*4+3]*inv;
    ((float4*)dst)[d4] = ov;
  }
}

// ---------------------------------------------------------------------------
// Workspace (floats): [0, 3*BHND) = q,k,v ; [3*BHND, +B*N*C) = attn out. 64 MB.
// ---------------------------------------------------------------------------
extern "C" void kernel_launch(void* const* d_in, const int* in_sizes, int n_in,
                              void* d_out, int out_size, void* d_ws, size_t ws_size,
                              hipStream_t stream)
{
  const float* x      = (const float*)d_in[0];
  const float* qkv_w  = (const float*)d_in[1];
  const float* qkv_b  = (const float*)d_in[2];
  const float* proj_w = (const float*)d_in[3];
  const float* proj_b = (const float*)d_in[4];
  float* out  = (float*)d_out;
  float* qkv  = (float*)d_ws;
  float* attn = qkv + (size_t)3*BHND;

  // QKV projection: [4096,1024] @ [1024,3072]^T -> scatter [3][B*H][N][D]
  gemm3_nt<1><<<dim3(32, 24), 256, 0, stream>>>(x, qkv_w, qkv_b, qkv, 3*C_, C_);
  // Windowed causal ALiBi attention -> [B,N,C]
  attn_win<<<dim3(1024), 64, 0, stream>>>(qkv, attn);
  // Output projection: [4096,1024] @ [1024,1024]^T + bias -> d_out
  gemm3_nt<0><<<dim3(32, 8), 256, 0, stream>>>(attn, proj_w, proj_b, out, C_, C_);
}

// Round 3
// 547.246 us; speedup vs baseline: 1.3117x; 1.3117x over previous
//
#include <hip/hip_runtime.h>
#include <hip/hip_bf16.h>
#include <cmath>

// ALiBi windowed-causal attention block, MI355X.
// R3: attention restructured — 4-way key-window split per query tile
//     (256-thread blocks, 4 waves, LDS LSE-combine), __launch_bounds__(256,2)
//     so q[]/o[] stay in VGPRs (R2 had VGPR=72 -> scratch thrash, 490us).
//     GEMMs unchanged from R2 (bf16x3 split MFMA, passed at absmax 7.8e-3).
// B=2, N=2048, C=1024, H=16, D=64, WINDOW=256, causal.
#define B_ 2
#define N_ 2048
#define C_ 1024
#define H_ 16
#define D_ 64
#define BHND (B_*H_*N_*D_)   // 4,194,304 elems per q/k/v tensor

typedef __attribute__((ext_vector_type(8))) short  bf16x8;   // 4 VGPR MFMA frag
typedef __attribute__((ext_vector_type(4))) float  f32x4;    // 4 VGPR acc frag
typedef __attribute__((ext_vector_type(4))) unsigned int uint4v;

// pack bf16(x0),bf16(x1) (truncation) into one u32: lo16=x0.top16, hi16=x1.top16
__device__ __forceinline__ unsigned pack_hi2(float x0, float x1) {
  return __builtin_amdgcn_perm(__float_as_uint(x1), __float_as_uint(x0), 0x07060302u);
}
__device__ __forceinline__ float trunc16(float x) {
  return __uint_as_float(__float_as_uint(x) & 0xFFFF0000u);
}
__device__ __forceinline__ void cvt8(const float4 u, const float4 v,
                                     uint4v& hi, uint4v& lo) {
  hi.x = pack_hi2(u.x, u.y); hi.y = pack_hi2(u.z, u.w);
  hi.z = pack_hi2(v.x, v.y); hi.w = pack_hi2(v.z, v.w);
  float l0 = u.x - trunc16(u.x), l1 = u.y - trunc16(u.y);
  float l2 = u.z - trunc16(u.z), l3 = u.w - trunc16(u.w);
  float l4 = v.x - trunc16(v.x), l5 = v.y - trunc16(v.y);
  float l6 = v.z - trunc16(v.z), l7 = v.w - trunc16(v.w);
  lo.x = pack_hi2(l0, l1); lo.y = pack_hi2(l2, l3);
  lo.z = pack_hi2(l4, l5); lo.w = pack_hi2(l6, l7);
}
// byte offset of (row, k-elem) in a [128][64]-bf16 tile, XOR-swizzled.
__device__ __forceinline__ int swz(int row, int kelem) {
  return ((row << 7) + (kelem << 1)) ^ ((row & 7) << 4);
}

// ---------------------------------------------------------------------------
// out = A @ Bw^T + bias via bf16x3 MFMA. A:[M,K] fp32 row-major, Bw:[Nc,K].
// MODE 0: direct store. MODE 1: scatter cols into qkv [3][B*H][N][D].
// 128x128 tile, BK=64, 256 threads = 4 waves (2x2), 64x64 out per wave.
// (unchanged from R2 — verified correct)
// ---------------------------------------------------------------------------
template<int MODE>
__global__ __launch_bounds__(256, 2)
void gemm3_nt(const float* __restrict__ A, const float* __restrict__ Bw,
              const float* __restrict__ bias, float* __restrict__ Cd,
              int Ncols, int K)
{
  __shared__ char smem[65536];
  char* Ah = smem;          char* Al = smem + 16384;
  char* Bh = smem + 32768;  char* Bl = smem + 49152;

  const int t    = threadIdx.x;
  const int lane = t & 63;
  const int w    = t >> 6;
  const int wm   = w >> 1, wn = w & 1;
  const int mb   = blockIdx.x, nb = blockIdx.y;

  const int srow = t >> 1;
  const int skh  = (t & 1) * 32;
  const float* Ag = A  + (size_t)(mb*128 + srow)*K + skh;
  const float* Bg = Bw + (size_t)(nb*128 + srow)*K + skh;

  f32x4 acc[4][4];
  #pragma unroll
  for (int m = 0; m < 4; ++m)
    #pragma unroll
    for (int n = 0; n < 4; ++n) acc[m][n] = (f32x4)0.f;

  float4 fa[8], fb[8];
  {
    const float4* ap = (const float4*)Ag;
    const float4* bp = (const float4*)Bg;
    #pragma unroll
    for (int i = 0; i < 8; ++i) { fa[i] = ap[i]; fb[i] = bp[i]; }
  }

  const int fr = lane & 15;
  const int fg = lane >> 4;
  const int nkt = K / 64;

  for (int kt = 0; kt < nkt; ++kt) {
    __syncthreads();
    #pragma unroll
    for (int c = 0; c < 4; ++c) {
      uint4v hi, lo;
      const int off = swz(srow, skh + c*8);
      cvt8(fa[2*c], fa[2*c+1], hi, lo);
      *(uint4v*)(Ah + off) = hi;  *(uint4v*)(Al + off) = lo;
      cvt8(fb[2*c], fb[2*c+1], hi, lo);
      *(uint4v*)(Bh + off) = hi;  *(uint4v*)(Bl + off) = lo;
    }
    __syncthreads();
    if (kt + 1 < nkt) {
      const float4* ap = (const float4*)(Ag + (kt+1)*64);
      const float4* bp = (const float4*)(Bg + (kt+1)*64);
      #pragma unroll
      for (int i = 0; i < 8; ++i) { fa[i] = ap[i]; fb[i] = bp[i]; }
    }
    #pragma unroll
    for (int ks = 0; ks < 2; ++ks) {
      const int ke = ks*32 + fg*8;
      bf16x8 ah[4], al[4];
      #pragma unroll
      for (int m = 0; m < 4; ++m) {
        const int off = swz(wm*64 + m*16 + fr, ke);
        ah[m] = *(const bf16x8*)(Ah + off);
        al[m] = *(const bf16x8*)(Al + off);
      }
      #pragma unroll
      for (int n = 0; n < 4; ++n) {
        const int off = swz(wn*64 + n*16 + fr, ke);
        const bf16x8 bh = *(const bf16x8*)(Bh + off);
        const bf16x8 bl = *(const bf16x8*)(Bl + off);
        #pragma unroll
        for (int m = 0; m < 4; ++m) {
          acc[m][n] = __builtin_amdgcn_mfma_f32_16x16x32_bf16(ah[m], bh, acc[m][n], 0, 0, 0);
          acc[m][n] = __builtin_amdgcn_mfma_f32_16x16x32_bf16(al[m], bh, acc[m][n], 0, 0, 0);
          acc[m][n] = __builtin_amdgcn_mfma_f32_16x16x32_bf16(ah[m], bl, acc[m][n], 0, 0, 0);
        }
      }
    }
  }

  #pragma unroll
  for (int n = 0; n < 4; ++n) {
    const int col = nb*128 + wn*64 + n*16 + fr;
    const float bb = bias[col];
    int which = 0, hh = 0, dd = 0;
    if (MODE == 1) { which = col >> 10; hh = (col >> 6) & 15; dd = col & 63; }
    #pragma unroll
    for (int m = 0; m < 4; ++m) {
      const int row0 = mb*128 + wm*64 + m*16 + fg*4;
      #pragma unroll
      for (int j = 0; j < 4; ++j) {
        const int row = row0 + j;
        const float val = acc[m][n][j] + bb;
        if (MODE == 0) {
          Cd[(size_t)row*Ncols + col] = val;
        } else {
          const int b = row >> 11, i = row & 2047;
          Cd[(size_t)which*BHND + (((size_t)(b*H_ + hh))*N_ + i)*D_ + dd] = val;
        }
      }
    }
  }
}

// ---------------------------------------------------------------------------
// Windowed causal ALiBi attention, 4-way split-K(window).
// Block = 256 threads = 4 waves, one 64-query tile of one (b,h) per block.
// Wave w handles quarter w of the tile's key range; query-per-lane with
// online softmax (q[64], o[64] in registers — launch_bounds(256,2) keeps the
// VGPR cap at 256 so nothing spills). Partials merged via LDS: waves 1-3
// write (m,l,o) to LDS, wave 0 merges in-register and stores.
// Grid = 1024 blocks -> 4096 waves (4x R2) -> ~8 waves/CU.
// ---------------------------------------------------------------------------
__global__ __launch_bounds__(256, 2)
void attn_win(const float* __restrict__ qkv, float* __restrict__ attn_out)
{
  __shared__ float m_s[4][64];
  __shared__ float l_s[4][64];
  __shared__ float o_s[3][64][68];   // waves 1..3; 68-pad: 16B rows, bank-spread

  const int t    = threadIdx.x;
  const int lane = t & 63;
  const int w    = t >> 6;
  const int qt   = blockIdx.x & 31;
  const int bh   = blockIdx.x >> 5;
  const int h    = bh & 15;
  const int i    = qt*64 + lane;

  const float* qrow  = qkv + ((size_t)bh*N_ + i)*D_;
  const float* kbase = qkv + (size_t)BHND + (size_t)bh*N_*D_;
  const float* vbase = kbase + (size_t)BHND;

  float q[64];
  #pragma unroll
  for (int d4 = 0; d4 < 16; ++d4) {
    float4 qv = ((const float4*)qrow)[d4];
    q[d4*4+0] = qv.x; q[d4*4+1] = qv.y; q[d4*4+2] = qv.z; q[d4*4+3] = qv.w;
  }
  float o[64];
  #pragma unroll
  for (int d = 0; d < 64; ++d) o[d] = 0.f;
  float mrun = -1e30f, lrun = 0.f;
  const float slope = exp2f(-0.5f * (float)(h + 1));

  const int jlo   = max(0, qt*64 - 255);
  const int jhi   = qt*64 + 63;
  const int chunk = (jhi - jlo + 4) >> 2;
  const int jbeg  = jlo + w*chunk;
  const int jend  = min(jbeg + chunk, jhi + 1);

  #pragma unroll 2
  for (int j = jbeg; j < jend; ++j) {
    const float4* krow = (const float4*)(kbase + (size_t)j*D_);
    float s0 = 0.f, s1 = 0.f, s2 = 0.f, s3 = 0.f;   // 4 chains: dot latency /4
    #pragma unroll
    for (int d4 = 0; d4 < 16; ++d4) {
      float4 kv = krow[d4];
      s0 = fmaf(q[d4*4+0], kv.x, s0);
      s1 = fmaf(q[d4*4+1], kv.y, s1);
      s2 = fmaf(q[d4*4+2], kv.z, s2);
      s3 = fmaf(q[d4*4+3], kv.w, s3);
    }
    float s = ((s0 + s1) + (s2 + s3));
    s = s*0.125f + slope*(float)(j - i);         // SCALE + alibi (rel = j-i)
    if (j <= i && j >= i - 255) {                // causal + sliding window
      const float mn   = fmaxf(mrun, s);
      const float corr = __expf(mrun - mn);
      const float p    = __expf(s - mn);
      lrun = lrun*corr + p;
      mrun = mn;
      const float4* vrow = (const float4*)(vbase + (size_t)j*D_);
      #pragma unroll
      for (int d4 = 0; d4 < 16; ++d4) {
        float4 vv = vrow[d4];
        o[d4*4+0] = fmaf(p, vv.x, o[d4*4+0]*corr);
        o[d4*4+1] = fmaf(p, vv.y, o[d4*4+1]*corr);
        o[d4*4+2] = fmaf(p, vv.z, o[d4*4+2]*corr);
        o[d4*4+3] = fmaf(p, vv.w, o[d4*4+3]*corr);
      }
    }
  }

  // ---- LSE combine: waves 1-3 spill partials, wave 0 merges ----
  m_s[w][lane] = mrun;
  l_s[w][lane] = lrun;
  if (w > 0) {
    #pragma unroll
    for (int d4 = 0; d4 < 16; ++d4) {
      float4 ov; ov.x = o[d4*4+0]; ov.y = o[d4*4+1];
      ov.z = o[d4*4+2]; ov.w = o[d4*4+3];
      *(float4*)&o_s[w-1][lane][d4*4] = ov;
    }
  }
  __syncthreads();
  if (w == 0) {
    const float m1 = m_s[1][lane], m2 = m_s[2][lane], m3 = m_s[3][lane];
    const float M  = fmaxf(fmaxf(mrun, m1), fmaxf(m2, m3));
    const float e0 = __expf(mrun - M);
    const float e1 = __expf(m1 - M);
    const float e2 = __expf(m2 - M);
    const float e3 = __expf(m3 - M);
    const float L  = lrun*e0 + l_s[1][lane]*e1 + l_s[2][lane]*e2 + l_s[3][lane]*e3;
    const float inv = 1.f / L;
    const int b = bh >> 4;
    float* dst = attn_out + ((size_t)b*N_ + i)*C_ + h*D_;   // [B,N,H*D]
    #pragma unroll
    for (int d4 = 0; d4 < 16; ++d4) {
      float4 p1 = *(const float4*)&o_s[0][lane][d4*4];
      float4 p2 = *(const float4*)&o_s[1][lane][d4*4];
      float4 p3 = *(const float4*)&o_s[2][lane][d4*4];
      float4 ov;
      ov.x = (o[d4*4+0]*e0 + p1.x*e1 + p2.x*e2 + p3.x*e3) * inv;
      ov.y = (o[d4*4+1]*e0 + p1.y*e1 + p2.y*e2 + p3.y*e3) * inv;
      ov.z = (o[d4*4+2]*e0 + p1.z*e1 + p2.z*e2 + p3.z*e3) * inv;
      ov.w = (o[d4*4+3]*e0 + p1.w*e1 + p2.w*e2 + p3.w*e3) * inv;
      ((float4*)dst)[d4] = ov;
    }
  }
}

// ---------------------------------------------------------------------------
// Workspace (floats): [0, 3*BHND) = q,k,v ; [3*BHND, +B*N*C) = attn out. 64 MB.
// ---------------------------------------------------------------------------
extern "C" void kernel_launch(void* const* d_in, const int* in_sizes, int n_in,
                              void* d_out, int out_size, void* d_ws, size_t ws_size,
                              hipStream_t stream)
{
  const float* x      = (const float*)d_in[0];
  const float* qkv_w  = (const float*)d_in[1];
  const float* qkv_b  = (const float*)d_in[2];
  const float* proj_w = (const float*)d_in[3];
  const float* proj_b = (const float*)d_in[4];
  float* out  = (float*)d_out;
  float* qkv  = (float*)d_ws;
  float* attn = qkv + (size_t)3*BHND;

  // QKV projection: [4096,1024] @ [1024,3072]^T -> scatter [3][B*H][N][D]
  gemm3_nt<1><<<dim3(32, 24), 256, 0, stream>>>(x, qkv_w, qkv_b, qkv, 3*C_, C_);
  // Windowed causal ALiBi attention -> [B,N,C]
  attn_win<<<dim3(1024), 256, 0, stream>>>(qkv, attn);
  // Output projection: [4096,1024] @ [1024,1024]^T + bias -> d_out
  gemm3_nt<0><<<dim3(32, 8), 256, 0, stream>>>(attn, proj_w, proj_b, out, C_, C_);
}

// Round 10
// 285.460 us; speedup vs baseline: 2.5147x; 1.9171x over previous
//
#include <hip/hip_runtime.h>
#include <hip/hip_bf16.h>
#include <cmath>

// ALiBi windowed-causal attention block, MI355X.
// R4 (sixth resubmit — GPU timeouts, never ran): attention moved to MFMA
//     (flash-style, bf16x3 hi/lo split, swapped QK^T, XOR-swizzled LDS tiles,
//     V staged transposed, K/V reg-prefetch). Fragment patterns identical to
//     the validated gemm3_nt kernel. GEMMs unchanged from R2 (validated).
// B=2, N=2048, C=1024, H=16, D=64, WINDOW=256, causal.
#define B_ 2
#define N_ 2048
#define C_ 1024
#define H_ 16
#define D_ 64
#define BHND (B_*H_*N_*D_)   // 4,194,304 elems per q/k/v tensor

typedef __attribute__((ext_vector_type(8))) short  bf16x8;   // 4 VGPR MFMA frag
typedef __attribute__((ext_vector_type(4))) float  f32x4;    // 4 VGPR acc frag
typedef __attribute__((ext_vector_type(4))) unsigned int uint4v;
typedef __attribute__((ext_vector_type(2))) unsigned int uint2v;

// pack bf16(x0),bf16(x1) (truncation) into one u32: lo16=x0.top16, hi16=x1.top16
__device__ __forceinline__ unsigned pack_hi2(float x0, float x1) {
  return __builtin_amdgcn_perm(__float_as_uint(x1), __float_as_uint(x0), 0x07060302u);
}
__device__ __forceinline__ float trunc16(float x) {
  return __uint_as_float(__float_as_uint(x) & 0xFFFF0000u);
}
__device__ __forceinline__ void cvt8(const float4 u, const float4 v,
                                     uint4v& hi, uint4v& lo) {
  hi.x = pack_hi2(u.x, u.y); hi.y = pack_hi2(u.z, u.w);
  hi.z = pack_hi2(v.x, v.y); hi.w = pack_hi2(v.z, v.w);
  float l0 = u.x - trunc16(u.x), l1 = u.y - trunc16(u.y);
  float l2 = u.z - trunc16(u.z), l3 = u.w - trunc16(u.w);
  float l4 = v.x - trunc16(v.x), l5 = v.y - trunc16(v.y);
  float l6 = v.z - trunc16(v.z), l7 = v.w - trunc16(v.w);
  lo.x = pack_hi2(l0, l1); lo.y = pack_hi2(l2, l3);
  lo.z = pack_hi2(l4, l5); lo.w = pack_hi2(l6, l7);
}
// byte offset of (row, k-elem) in a [*][64]-bf16 row-major tile, XOR-swizzled
// so 16-row column slices of ds_read_b128 spread across all 32 banks.
__device__ __forceinline__ int swz(int row, int kelem) {
  return ((row << 7) + (kelem << 1)) ^ ((row & 7) << 4);
}

// ---------------------------------------------------------------------------
// out = A @ Bw^T + bias via bf16x3 MFMA. A:[M,K] fp32 row-major, Bw:[Nc,K].
// MODE 0: direct store. MODE 1: scatter cols into qkv [3][B*H][N][D].
// 128x128 tile, BK=64, 256 threads = 4 waves (2x2), 64x64 out per wave.
// (unchanged — validated)
// ---------------------------------------------------------------------------
template<int MODE>
__global__ __launch_bounds__(256, 2)
void gemm3_nt(const float* __restrict__ A, const float* __restrict__ Bw,
              const float* __restrict__ bias, float* __restrict__ Cd,
              int Ncols, int K)
{
  __shared__ char smem[65536];
  char* Ah = smem;          char* Al = smem + 16384;
  char* Bh = smem + 32768;  char* Bl = smem + 49152;

  const int t    = threadIdx.x;
  const int lane = t & 63;
  const int w    = t >> 6;
  const int wm   = w >> 1, wn = w & 1;
  const int mb   = blockIdx.x, nb = blockIdx.y;

  const int srow = t >> 1;
  const int skh  = (t & 1) * 32;
  const float* Ag = A  + (size_t)(mb*128 + srow)*K + skh;
  const float* Bg = Bw + (size_t)(nb*128 + srow)*K + skh;

  f32x4 acc[4][4];
  #pragma unroll
  for (int m = 0; m < 4; ++m)
    #pragma unroll
    for (int n = 0; n < 4; ++n) acc[m][n] = (f32x4)0.f;

  float4 fa[8], fb[8];
  {
    const float4* ap = (const float4*)Ag;
    const float4* bp = (const float4*)Bg;
    #pragma unroll
    for (int i = 0; i < 8; ++i) { fa[i] = ap[i]; fb[i] = bp[i]; }
  }

  const int fr = lane & 15;
  const int fg = lane >> 4;
  const int nkt = K / 64;

  for (int kt = 0; kt < nkt; ++kt) {
    __syncthreads();
    #pragma unroll
    for (int cc = 0; cc < 4; ++cc) {
      uint4v hi, lo;
      const int off = swz(srow, skh + cc*8);
      cvt8(fa[2*cc], fa[2*cc+1], hi, lo);
      *(uint4v*)(Ah + off) = hi;  *(uint4v*)(Al + off) = lo;
      cvt8(fb[2*cc], fb[2*cc+1], hi, lo);
      *(uint4v*)(Bh + off) = hi;  *(uint4v*)(Bl + off) = lo;
    }
    __syncthreads();
    if (kt + 1 < nkt) {
      const float4* ap = (const float4*)(Ag + (kt+1)*64);
      const float4* bp = (const float4*)(Bg + (kt+1)*64);
      #pragma unroll
      for (int i = 0; i < 8; ++i) { fa[i] = ap[i]; fb[i] = bp[i]; }
    }
    #pragma unroll
    for (int ks = 0; ks < 2; ++ks) {
      const int ke = ks*32 + fg*8;
      bf16x8 ah[4], al[4];
      #pragma unroll
      for (int m = 0; m < 4; ++m) {
        const int off = swz(wm*64 + m*16 + fr, ke);
        ah[m] = *(const bf16x8*)(Ah + off);
        al[m] = *(const bf16x8*)(Al + off);
      }
      #pragma unroll
      for (int n = 0; n < 4; ++n) {
        const int off = swz(wn*64 + n*16 + fr, ke);
        const bf16x8 bh = *(const bf16x8*)(Bh + off);
        const bf16x8 bl = *(const bf16x8*)(Bl + off);
        #pragma unroll
        for (int m = 0; m < 4; ++m) {
          acc[m][n] = __builtin_amdgcn_mfma_f32_16x16x32_bf16(ah[m], bh, acc[m][n], 0, 0, 0);
          acc[m][n] = __builtin_amdgcn_mfma_f32_16x16x32_bf16(al[m], bh, acc[m][n], 0, 0, 0);
          acc[m][n] = __builtin_amdgcn_mfma_f32_16x16x32_bf16(ah[m], bl, acc[m][n], 0, 0, 0);
        }
      }
    }
  }

  #pragma unroll
  for (int n = 0; n < 4; ++n) {
    const int col = nb*128 + wn*64 + n*16 + fr;
    const float bb = bias[col];
    int which = 0, hh = 0, dd = 0;
    if (MODE == 1) { which = col >> 10; hh = (col >> 6) & 15; dd = col & 63; }
    #pragma unroll
    for (int m = 0; m < 4; ++m) {
      const int row0 = mb*128 + wm*64 + m*16 + fg*4;
      #pragma unroll
      for (int j = 0; j < 4; ++j) {
        const int row = row0 + j;
        const float val = acc[m][n][j] + bb;
        if (MODE == 0) {
          Cd[(size_t)row*Ncols + col] = val;
        } else {
          const int b = row >> 11, i = row & 2047;
          Cd[(size_t)which*BHND + (((size_t)(b*H_ + hh))*N_ + i)*D_ + dd] = val;
        }
      }
    }
  }
}

// ---------------------------------------------------------------------------
// MFMA flash attention with ALiBi + causal + sliding window.
// Block = one (b,h) x 64-query tile, 256 threads = 4 waves; wave w owns the
// 16-query strip w*16..w*16+15. Loop over <=5 aligned 64-key tiles.
// Per tile: S^T = mfma(K,Q) (64 keys x 16 q per wave, q = C-layout column),
// online softmax (row-max = own-16 + shfl_xor 16/32), P -> LDS hi/lo bf16,
// O += mfma(P,V) with V staged TRANSPOSED [d][key]. All tiles swz()-swizzled.
// Masked s = -1e30, m init -1e20 (all-masked tile => corr=1, p=0: safe).
// ---------------------------------------------------------------------------
__global__ __launch_bounds__(256, 2)
void attn_mfma(const float* __restrict__ qkv, float* __restrict__ attn_out)
{
  __shared__ char smem[65536];
  char* Qh = smem;             // [64 q ][64 d ] bf16 hi
  char* Ql = smem + 8192;
  char* Kh = smem + 16384;     // [64 key][64 d ]
  char* Kl = smem + 24576;
  char* Vh = smem + 32768;     // V^T [64 d][64 key]
  char* Vl = smem + 40960;
  char* Ph = smem + 49152;     // per-wave [16 q][64 key] at w*2048
  char* Pl = smem + 57344;

  const int t    = threadIdx.x;
  const int lane = t & 63;
  const int w    = t >> 6;
  const int g    = lane >> 4;
  const int c    = lane & 15;
  const int qt   = blockIdx.x & 31;
  const int bh   = blockIdx.x >> 5;
  const int h    = bh & 15;
  const int b    = bh >> 4;

  const float* qg = qkv + (size_t)bh*N_*D_;
  const float* kg = qg + (size_t)BHND;
  const float* vg = kg + (size_t)BHND;

  const float slope = exp2f(-0.5f*(float)(h+1));
  const int kt0 = max(0, qt - 4);
  const int ktN = qt;

  // staging roles
  const int srow = t >> 2;          // 0..63  (K/Q row)
  const int scq  = (t & 3) * 16;    // d-quad base
  const int vkey = t & 63;          // V^T: key column
  const int vdb  = (t >> 6) * 16;   // V^T: d-range base

  // ---- stage Q + K/V(kt0) ----
  {
    const float4* qp = (const float4*)(qg + (size_t)(qt*64 + srow)*D_ + scq);
    float4 q0=qp[0], q1=qp[1], q2=qp[2], q3=qp[3];
    const float4* kp = (const float4*)(kg + (size_t)(kt0*64 + srow)*D_ + scq);
    float4 k0=kp[0], k1=kp[1], k2=kp[2], k3=kp[3];
    const float4* vp = (const float4*)(vg + (size_t)(kt0*64 + vkey)*D_ + vdb);
    float4 v0=vp[0], v1=vp[1], v2=vp[2], v3=vp[3];
    uint4v hi, lo;
    cvt8(q0,q1,hi,lo); *(uint4v*)(Qh+swz(srow,scq  ))=hi; *(uint4v*)(Ql+swz(srow,scq  ))=lo;
    cvt8(q2,q3,hi,lo); *(uint4v*)(Qh+swz(srow,scq+8))=hi; *(uint4v*)(Ql+swz(srow,scq+8))=lo;
    cvt8(k0,k1,hi,lo); *(uint4v*)(Kh+swz(srow,scq  ))=hi; *(uint4v*)(Kl+swz(srow,scq  ))=lo;
    cvt8(k2,k3,hi,lo); *(uint4v*)(Kh+swz(srow,scq+8))=hi; *(uint4v*)(Kl+swz(srow,scq+8))=lo;
    const float vv[16] = {v0.x,v0.y,v0.z,v0.w, v1.x,v1.y,v1.z,v1.w,
                          v2.x,v2.y,v2.z,v2.w, v3.x,v3.y,v3.z,v3.w};
    #pragma unroll
    for (int d16 = 0; d16 < 16; ++d16) {
      const int d  = vdb + d16;
      const int off = swz(d, vkey);
      const unsigned xu = __float_as_uint(vv[d16]);
      *(unsigned short*)(Vh + off) = (unsigned short)(xu >> 16);
      const float xt = __uint_as_float(xu & 0xFFFF0000u);
      *(unsigned short*)(Vl + off) = (unsigned short)(__float_as_uint(vv[d16] - xt) >> 16);
    }
  }
  __syncthreads();

  // hoist Q B-frags (loop-invariant): col=q=c within this wave's strip
  bf16x8 qbh[2], qbl[2];
  #pragma unroll
  for (int ks = 0; ks < 2; ++ks) {
    const int off = swz(w*16 + c, ks*32 + g*8);
    qbh[ks] = *(const bf16x8*)(Qh + off);
    qbl[ks] = *(const bf16x8*)(Ql + off);
  }

  // prefetch K/V(kt0+1)
  float4 pk[4], pvv[4];
  if (kt0 < ktN) {
    const float4* kp = (const float4*)(kg + (size_t)((kt0+1)*64 + srow)*D_ + scq);
    const float4* vp = (const float4*)(vg + (size_t)((kt0+1)*64 + vkey)*D_ + vdb);
    #pragma unroll
    for (int i = 0; i < 4; ++i) { pk[i] = kp[i]; pvv[i] = vp[i]; }
  }

  f32x4 co[4];
  #pragma unroll
  for (int n = 0; n < 4; ++n) co[n] = (f32x4)0.f;
  float mrun = -1e20f, lrun = 0.f;
  const int iq = qt*64 + w*16 + c;          // this lane's query (softmax phase)
  const int pbase = w*2048;

  for (int kt = kt0; ; ++kt) {
    // ---- S^T = K . Q^T : 4 key-subtile frags ----
    f32x4 sc[4];
    #pragma unroll
    for (int f = 0; f < 4; ++f) sc[f] = (f32x4)0.f;
    #pragma unroll
    for (int ks = 0; ks < 2; ++ks) {
      #pragma unroll
      for (int f = 0; f < 4; ++f) {
        const int off = swz(f*16 + c, ks*32 + g*8);
        const bf16x8 ah = *(const bf16x8*)(Kh + off);
        const bf16x8 al = *(const bf16x8*)(Kl + off);
        sc[f] = __builtin_amdgcn_mfma_f32_16x16x32_bf16(ah, qbh[ks], sc[f], 0,0,0);
        sc[f] = __builtin_amdgcn_mfma_f32_16x16x32_bf16(al, qbh[ks], sc[f], 0,0,0);
        sc[f] = __builtin_amdgcn_mfma_f32_16x16x32_bf16(ah, qbl[ks], sc[f], 0,0,0);
      }
    }
    // ---- online softmax; lane owns q=c with 16 key-values ----
    float sv[4][4];
    float mt = -1e30f;
    #pragma unroll
    for (int f = 0; f < 4; ++f)
      #pragma unroll
      for (int r = 0; r < 4; ++r) {
        const int rel = kt*64 + f*16 + g*4 + r - iq;
        float s = fmaf(sc[f][r], 0.125f, slope*(float)rel);
        s = (rel > 0 || rel < -255) ? -1e30f : s;
        sv[f][r] = s;
        mt = fmaxf(mt, s);
      }
    mt = fmaxf(mt, __shfl_xor(mt, 16));
    mt = fmaxf(mt, __shfl_xor(mt, 32));
    const float mnew = fmaxf(mrun, mt);
    const float corr = __expf(mrun - mnew);
    mrun = mnew;
    float pw[4][4];
    float psum = 0.f;
    #pragma unroll
    for (int f = 0; f < 4; ++f)
      #pragma unroll
      for (int r = 0; r < 4; ++r) {
        const float p = __expf(sv[f][r] - mnew);
        pw[f][r] = p;
        psum += p;
      }
    psum += __shfl_xor(psum, 16);
    psum += __shfl_xor(psum, 32);
    lrun = lrun*corr + psum;
    // ---- P -> LDS (hi/lo bf16), row=q=c, col=key ----
    #pragma unroll
    for (int f = 0; f < 4; ++f) {
      const int off = swz(c, f*16 + g*4);
      uint2v ph2, pl2;
      ph2.x = pack_hi2(pw[f][0], pw[f][1]);
      ph2.y = pack_hi2(pw[f][2], pw[f][3]);
      pl2.x = pack_hi2(pw[f][0]-trunc16(pw[f][0]), pw[f][1]-trunc16(pw[f][1]));
      pl2.y = pack_hi2(pw[f][2]-trunc16(pw[f][2]), pw[f][3]-trunc16(pw[f][3]));
      *(uint2v*)(Ph + pbase + off) = ph2;
      *(uint2v*)(Pl + pbase + off) = pl2;
    }
    // ---- rescale O by per-q corr (O rows are q=g*4+r) ----
    const float c0 = __shfl(corr, g*4+0);
    const float c1 = __shfl(corr, g*4+1);
    const float c2 = __shfl(corr, g*4+2);
    const float c3 = __shfl(corr, g*4+3);
    #pragma unroll
    for (int n = 0; n < 4; ++n) {
      co[n][0] *= c0; co[n][1] *= c1; co[n][2] *= c2; co[n][3] *= c3;
    }
    // ---- O += P . V ----
    #pragma unroll
    for (int ks = 0; ks < 2; ++ks) {
      const int poff = swz(c, ks*32 + g*8);
      const bf16x8 pah = *(const bf16x8*)(Ph + pbase + poff);
      const bf16x8 pal = *(const bf16x8*)(Pl + pbase + poff);
      #pragma unroll
      for (int n = 0; n < 4; ++n) {
        const int voff = swz(n*16 + c, ks*32 + g*8);
        const bf16x8 vbh = *(const bf16x8*)(Vh + voff);
        const bf16x8 vbl = *(const bf16x8*)(Vl + voff);
        co[n] = __builtin_amdgcn_mfma_f32_16x16x32_bf16(pah, vbh, co[n], 0,0,0);
        co[n] = __builtin_amdgcn_mfma_f32_16x16x32_bf16(pal, vbh, co[n], 0,0,0);
        co[n] = __builtin_amdgcn_mfma_f32_16x16x32_bf16(pah, vbl, co[n], 0,0,0);
      }
    }
    if (kt == ktN) break;
    __syncthreads();              // all waves done reading K/V(kt)
    // write prefetched K/V(kt+1)
    {
      uint4v hi, lo;
      cvt8(pk[0], pk[1], hi, lo);
      *(uint4v*)(Kh+swz(srow,scq  ))=hi; *(uint4v*)(Kl+swz(srow,scq  ))=lo;
      cvt8(pk[2], pk[3], hi, lo);
      *(uint4v*)(Kh+swz(srow,scq+8))=hi; *(uint4v*)(Kl+swz(srow,scq+8))=lo;
      const float vv[16] = {pvv[0].x,pvv[0].y,pvv[0].z,pvv[0].w,
                            pvv[1].x,pvv[1].y,pvv[1].z,pvv[1].w,
                            pvv[2].x,pvv[2].y,pvv[2].z,pvv[2].w,
                            pvv[3].x,pvv[3].y,pvv[3].z,pvv[3].w};
      #pragma unroll
      for (int d16 = 0; d16 < 16; ++d16) {
        const int d  = vdb + d16;
        const int off = swz(d, vkey);
        const unsigned xu = __float_as_uint(vv[d16]);
        *(unsigned short*)(Vh + off) = (unsigned short)(xu >> 16);
        const float xt = __uint_as_float(xu & 0xFFFF0000u);
        *(unsigned short*)(Vl + off) = (unsigned short)(__float_as_uint(vv[d16] - xt) >> 16);
      }
    }
    __syncthreads();              // staged tile visible
    if (kt + 1 < ktN) {           // prefetch K/V(kt+2)
      const float4* kp = (const float4*)(kg + (size_t)((kt+2)*64 + srow)*D_ + scq);
      const float4* vp = (const float4*)(vg + (size_t)((kt+2)*64 + vkey)*D_ + vdb);
      #pragma unroll
      for (int i = 0; i < 4; ++i) { pk[i] = kp[i]; pvv[i] = vp[i]; }
    }
  }

  // ---- epilogue: O rows are q=g*4+r; divide by l[q], store ----
  float linv[4];
  #pragma unroll
  for (int r = 0; r < 4; ++r) linv[r] = 1.f / __shfl(lrun, g*4+r);
  #pragma unroll
  for (int n = 0; n < 4; ++n)
    #pragma unroll
    for (int r = 0; r < 4; ++r) {
      const int qrow = qt*64 + w*16 + g*4 + r;
      attn_out[((size_t)b*N_ + qrow)*C_ + h*64 + n*16 + c] = co[n][r] * linv[r];
    }
}

// ---------------------------------------------------------------------------
// Workspace (floats): [0, 3*BHND) = q,k,v ; [3*BHND, +B*N*C) = attn out. 64 MB.
// ---------------------------------------------------------------------------
extern "C" void kernel_launch(void* const* d_in, const int* in_sizes, int n_in,
                              void* d_out, int out_size, void* d_ws, size_t ws_size,
                              hipStream_t stream)
{
  const float* x      = (const float*)d_in[0];
  const float* qkv_w  = (const float*)d_in[1];
  const float* qkv_b  = (const float*)d_in[2];
  const float* proj_w = (const float*)d_in[3];
  const float* proj_b = (const float*)d_in[4];
  float* out  = (float*)d_out;
  float* qkv  = (float*)d_ws;
  float* attn = qkv + (size_t)3*BHND;

  // QKV projection: [4096,1024] @ [1024,3072]^T -> scatter [3][B*H][N][D]
  gemm3_nt<1><<<dim3(32, 24), 256, 0, stream>>>(x, qkv_w, qkv_b, qkv, 3*C_, C_);
  // MFMA flash attention -> [B,N,C]
  attn_mfma<<<dim3(1024), 256, 0, stream>>>(qkv, attn);
  // Output projection: [4096,1024] @ [1024,1024]^T + bias -> d_out
  gemm3_nt<0><<<dim3(32, 8), 256, 0, stream>>>(attn, proj_w, proj_b, out, C_, C_);
}

// Round 11
// 241.978 us; speedup vs baseline: 2.9665x; 1.1797x over previous
//
#include <hip/hip_runtime.h>
#include <hip/hip_bf16.h>
#include <cmath>

// ALiBi windowed-causal attention block, MI355X.
// R11: hoist all fp32->bf16(hi/lo) conversions out of the hot kernels.
//   - cvt_split kernels convert x, qkv_w, proj_w once per call.
//   - gemm_b3 stages pre-converted bf16 operands (pure copies, half bytes).
//   - QKV epilogue writes q/k/v as bf16 hi/lo; attn reads/writes bf16 hi/lo.
//   - All LDS layouts / fragments / MFMA order unchanged -> bit-identical.
//   - ws_size < 96 MiB => fall back to validated R4 path (285 us).
// B=2, N=2048, C=1024, H=16, D=64, WINDOW=256, causal.
#define B_ 2
#define N_ 2048
#define C_ 1024
#define H_ 16
#define D_ 64
#define BHND (B_*H_*N_*D_)   // 4,194,304 elems per q/k/v tensor
#define BNC  (B_*N_*C_)      // 4,194,304

typedef __attribute__((ext_vector_type(8))) short  bf16x8;   // 4 VGPR MFMA frag
typedef __attribute__((ext_vector_type(4))) float  f32x4;    // 4 VGPR acc frag
typedef __attribute__((ext_vector_type(4))) unsigned int uint4v;
typedef __attribute__((ext_vector_type(2))) unsigned int uint2v;
typedef unsigned short ushort_t;

__device__ __forceinline__ unsigned pack_hi2(float x0, float x1) {
  return __builtin_amdgcn_perm(__float_as_uint(x1), __float_as_uint(x0), 0x07060302u);
}
__device__ __forceinline__ float trunc16(float x) {
  return __uint_as_float(__float_as_uint(x) & 0xFFFF0000u);
}
__device__ __forceinline__ void cvt8(const float4 u, const float4 v,
                                     uint4v& hi, uint4v& lo) {
  hi.x = pack_hi2(u.x, u.y); hi.y = pack_hi2(u.z, u.w);
  hi.z = pack_hi2(v.x, v.y); hi.w = pack_hi2(v.z, v.w);
  float l0 = u.x - trunc16(u.x), l1 = u.y - trunc16(u.y);
  float l2 = u.z - trunc16(u.z), l3 = u.w - trunc16(u.w);
  float l4 = v.x - trunc16(v.x), l5 = v.y - trunc16(v.y);
  float l6 = v.z - trunc16(v.z), l7 = v.w - trunc16(v.w);
  lo.x = pack_hi2(l0, l1); lo.y = pack_hi2(l2, l3);
  lo.z = pack_hi2(l4, l5); lo.w = pack_hi2(l6, l7);
}
// byte offset of (row,kelem) in [*][64]-bf16 tile, XOR-swizzled (validated).
__device__ __forceinline__ int swz(int row, int kelem) {
  return ((row << 7) + (kelem << 1)) ^ ((row & 7) << 4);
}

// ===========================================================================
// NEW PATH
// ===========================================================================

// fp32 -> (bf16 hi, bf16 lo), 4 elems/thread, grid-stride.
__global__ __launch_bounds__(256)
void cvt_split(const float* __restrict__ in, ushort_t* __restrict__ h,
               ushort_t* __restrict__ l, int n4)
{
  for (int i = blockIdx.x*256 + threadIdx.x; i < n4; i += gridDim.x*256) {
    const float4 v = ((const float4*)in)[i];
    uint2v hh, ll;
    hh.x = pack_hi2(v.x, v.y); hh.y = pack_hi2(v.z, v.w);
    ll.x = pack_hi2(v.x - trunc16(v.x), v.y - trunc16(v.y));
    ll.y = pack_hi2(v.z - trunc16(v.z), v.w - trunc16(v.w));
    *(uint2v*)(h + 4*(size_t)i) = hh;
    *(uint2v*)(l + 4*(size_t)i) = ll;
  }
}

// ---------------------------------------------------------------------------
// out = A @ B^T + bias, operands pre-split bf16 hi/lo ([M][K],[Nc][K] rows).
// MODE 0: fp32 store to Cf.  MODE 1: scatter bf16 hi/lo into qkv [3][B*H][N][D].
// Same tile/frag/MFMA structure as validated gemm3_nt; staging is pure copy.
// ---------------------------------------------------------------------------
template<int MODE>
__global__ __launch_bounds__(256, 2)
void gemm_b3(const ushort_t* __restrict__ Agh_, const ushort_t* __restrict__ Agl_,
             const ushort_t* __restrict__ Bgh_, const ushort_t* __restrict__ Bgl_,
             const float* __restrict__ bias, float* __restrict__ Cf,
             ushort_t* __restrict__ Ch, ushort_t* __restrict__ Cl,
             int Ncols, int K)
{
  __shared__ char smem[65536];
  char* Ah = smem;          char* Al = smem + 16384;
  char* Bh = smem + 32768;  char* Bl = smem + 49152;

  const int t    = threadIdx.x;
  const int lane = t & 63;
  const int w    = t >> 6;
  const int wm   = w >> 1, wn = w & 1;
  const int mb   = blockIdx.x, nb = blockIdx.y;

  const int srow = t >> 1;
  const int skh  = (t & 1) * 32;
  const ushort_t* Agh = Agh_ + (size_t)(mb*128 + srow)*K + skh;
  const ushort_t* Agl = Agl_ + (size_t)(mb*128 + srow)*K + skh;
  const ushort_t* Bgh = Bgh_ + (size_t)(nb*128 + srow)*K + skh;
  const ushort_t* Bgl = Bgl_ + (size_t)(nb*128 + srow)*K + skh;

  f32x4 acc[4][4];
  #pragma unroll
  for (int m = 0; m < 4; ++m)
    #pragma unroll
    for (int n = 0; n < 4; ++n) acc[m][n] = (f32x4)0.f;

  uint4v fah[4], fal[4], fbh[4], fbl[4];
  #pragma unroll
  for (int i = 0; i < 4; ++i) {
    fah[i] = *(const uint4v*)(Agh + i*8);
    fal[i] = *(const uint4v*)(Agl + i*8);
    fbh[i] = *(const uint4v*)(Bgh + i*8);
    fbl[i] = *(const uint4v*)(Bgl + i*8);
  }

  const int fr = lane & 15;
  const int fg = lane >> 4;
  const int nkt = K / 64;

  for (int kt = 0; kt < nkt; ++kt) {
    __syncthreads();
    #pragma unroll
    for (int cc = 0; cc < 4; ++cc) {
      const int off = swz(srow, skh + cc*8);
      *(uint4v*)(Ah + off) = fah[cc];  *(uint4v*)(Al + off) = fal[cc];
      *(uint4v*)(Bh + off) = fbh[cc];  *(uint4v*)(Bl + off) = fbl[cc];
    }
    __syncthreads();
    if (kt + 1 < nkt) {
      const int ko = (kt+1)*64;
      #pragma unroll
      for (int i = 0; i < 4; ++i) {
        fah[i] = *(const uint4v*)(Agh + ko + i*8);
        fal[i] = *(const uint4v*)(Agl + ko + i*8);
        fbh[i] = *(const uint4v*)(Bgh + ko + i*8);
        fbl[i] = *(const uint4v*)(Bgl + ko + i*8);
      }
    }
    #pragma unroll
    for (int ks = 0; ks < 2; ++ks) {
      const int ke = ks*32 + fg*8;
      bf16x8 ah[4], al[4];
      #pragma unroll
      for (int m = 0; m < 4; ++m) {
        const int off = swz(wm*64 + m*16 + fr, ke);
        ah[m] = *(const bf16x8*)(Ah + off);
        al[m] = *(const bf16x8*)(Al + off);
      }
      #pragma unroll
      for (int n = 0; n < 4; ++n) {
        const int off = swz(wn*64 + n*16 + fr, ke);
        const bf16x8 bh = *(const bf16x8*)(Bh + off);
        const bf16x8 bl = *(const bf16x8*)(Bl + off);
        #pragma unroll
        for (int m = 0; m < 4; ++m) {
          acc[m][n] = __builtin_amdgcn_mfma_f32_16x16x32_bf16(ah[m], bh, acc[m][n], 0, 0, 0);
          acc[m][n] = __builtin_amdgcn_mfma_f32_16x16x32_bf16(al[m], bh, acc[m][n], 0, 0, 0);
          acc[m][n] = __builtin_amdgcn_mfma_f32_16x16x32_bf16(ah[m], bl, acc[m][n], 0, 0, 0);
        }
      }
    }
  }

  #pragma unroll
  for (int n = 0; n < 4; ++n) {
    const int col = nb*128 + wn*64 + n*16 + fr;
    const float bb = bias[col];
    int which = 0, hh = 0, dd = 0;
    if (MODE == 1) { which = col >> 10; hh = (col >> 6) & 15; dd = col & 63; }
    #pragma unroll
    for (int m = 0; m < 4; ++m) {
      const int row0 = mb*128 + wm*64 + m*16 + fg*4;
      #pragma unroll
      for (int j = 0; j < 4; ++j) {
        const int row = row0 + j;
        const float val = acc[m][n][j] + bb;
        if (MODE == 0) {
          Cf[(size_t)row*Ncols + col] = val;
        } else {
          const int b = row >> 11, i = row & 2047;
          const size_t idx = (size_t)which*BHND + (((size_t)(b*H_ + hh))*N_ + i)*D_ + dd;
          Ch[idx] = (ushort_t)(__float_as_uint(val) >> 16);
          Cl[idx] = (ushort_t)(__float_as_uint(val - trunc16(val)) >> 16);
        }
      }
    }
  }
}

// ---------------------------------------------------------------------------
// MFMA flash attention, pre-split bf16 q/k/v in, bf16 hi/lo out.
// Identical structure to validated attn_mfma; staging is pure copy.
// ---------------------------------------------------------------------------
__global__ __launch_bounds__(256, 2)
void attn_b3(const ushort_t* __restrict__ qkvh, const ushort_t* __restrict__ qkvl,
             ushort_t* __restrict__ outh, ushort_t* __restrict__ outl)
{
  __shared__ char smem[65536];
  char* Qh = smem;             // [64 q ][64 d ]
  char* Ql = smem + 8192;
  char* Kh = smem + 16384;     // [64 key][64 d ]
  char* Kl = smem + 24576;
  char* Vh = smem + 32768;     // V^T [64 d][64 key]
  char* Vl = smem + 40960;
  char* Ph = smem + 49152;     // per-wave [16 q][64 key] at w*2048
  char* Pl = smem + 57344;

  const int t    = threadIdx.x;
  const int lane = t & 63;
  const int w    = t >> 6;
  const int g    = lane >> 4;
  const int c    = lane & 15;
  const int qt   = blockIdx.x & 31;
  const int bh   = blockIdx.x >> 5;
  const int h    = bh & 15;
  const int b    = bh >> 4;

  const ushort_t* qgh = qkvh + (size_t)bh*N_*D_;
  const ushort_t* qgl = qkvl + (size_t)bh*N_*D_;
  const ushort_t* kgh = qkvh + (size_t)BHND   + (size_t)bh*N_*D_;
  const ushort_t* kgl = qkvl + (size_t)BHND   + (size_t)bh*N_*D_;
  const ushort_t* vgh = qkvh + (size_t)2*BHND + (size_t)bh*N_*D_;
  const ushort_t* vgl = qkvl + (size_t)2*BHND + (size_t)bh*N_*D_;

  const float slope = exp2f(-0.5f*(float)(h+1));
  const int kt0 = max(0, qt - 4);
  const int ktN = qt;

  const int srow = t >> 2;          // 0..63 (Q/K row)
  const int scq  = (t & 3) * 16;    // d-quad base
  const int vkey = t & 63;          // V^T: key column
  const int vdb  = (t >> 6) * 16;   // V^T: d-range base

  // ---- stage Q + K/V(kt0): pure copies ----
  {
    const uint4v* qph = (const uint4v*)(qgh + (size_t)(qt*64 + srow)*D_ + scq);
    const uint4v* qpl = (const uint4v*)(qgl + (size_t)(qt*64 + srow)*D_ + scq);
    const uint4v* kph = (const uint4v*)(kgh + (size_t)(kt0*64 + srow)*D_ + scq);
    const uint4v* kpl = (const uint4v*)(kgl + (size_t)(kt0*64 + srow)*D_ + scq);
    const uint4v* vph = (const uint4v*)(vgh + (size_t)(kt0*64 + vkey)*D_ + vdb);
    const uint4v* vpl = (const uint4v*)(vgl + (size_t)(kt0*64 + vkey)*D_ + vdb);
    uint4v q0=qph[0], q1=qph[1], ql0=qpl[0], ql1=qpl[1];
    uint4v k0=kph[0], k1=kph[1], kl0=kpl[0], kl1=kpl[1];
    uint4v v0=vph[0], v1=vph[1], vl0=vpl[0], vl1=vpl[1];
    *(uint4v*)(Qh+swz(srow,scq))   = q0;  *(uint4v*)(Qh+swz(srow,scq+8)) = q1;
    *(uint4v*)(Ql+swz(srow,scq))   = ql0; *(uint4v*)(Ql+swz(srow,scq+8)) = ql1;
    *(uint4v*)(Kh+swz(srow,scq))   = k0;  *(uint4v*)(Kh+swz(srow,scq+8)) = k1;
    *(uint4v*)(Kl+swz(srow,scq))   = kl0; *(uint4v*)(Kl+swz(srow,scq+8)) = kl1;
    #pragma unroll
    for (int j = 0; j < 4; ++j) {
      const int d0 = vdb + 2*j, d1 = vdb + 8 + 2*j;
      unsigned wh = v0[j], wl = vl0[j];
      *(ushort_t*)(Vh + swz(d0,   vkey)) = (ushort_t)(wh & 0xffffu);
      *(ushort_t*)(Vh + swz(d0+1, vkey)) = (ushort_t)(wh >> 16);
      *(ushort_t*)(Vl + swz(d0,   vkey)) = (ushort_t)(wl & 0xffffu);
      *(ushort_t*)(Vl + swz(d0+1, vkey)) = (ushort_t)(wl >> 16);
      wh = v1[j]; wl = vl1[j];
      *(ushort_t*)(Vh + swz(d1,   vkey)) = (ushort_t)(wh & 0xffffu);
      *(ushort_t*)(Vh + swz(d1+1, vkey)) = (ushort_t)(wh >> 16);
      *(ushort_t*)(Vl + swz(d1,   vkey)) = (ushort_t)(wl & 0xffffu);
      *(ushort_t*)(Vl + swz(d1+1, vkey)) = (ushort_t)(wl >> 16);
    }
  }
  __syncthreads();

  // hoist Q B-frags (loop-invariant)
  bf16x8 qbh[2], qbl[2];
  #pragma unroll
  for (int ks = 0; ks < 2; ++ks) {
    const int off = swz(w*16 + c, ks*32 + g*8);
    qbh[ks] = *(const bf16x8*)(Qh + off);
    qbl[ks] = *(const bf16x8*)(Ql + off);
  }

  // prefetch K/V(kt0+1)
  uint4v pkh[2], pkl[2], pvh[2], pvl[2];
  if (kt0 < ktN) {
    const uint4v* kph = (const uint4v*)(kgh + (size_t)((kt0+1)*64 + srow)*D_ + scq);
    const uint4v* kpl = (const uint4v*)(kgl + (size_t)((kt0+1)*64 + srow)*D_ + scq);
    const uint4v* vph = (const uint4v*)(vgh + (size_t)((kt0+1)*64 + vkey)*D_ + vdb);
    const uint4v* vpl = (const uint4v*)(vgl + (size_t)((kt0+1)*64 + vkey)*D_ + vdb);
    pkh[0]=kph[0]; pkh[1]=kph[1]; pkl[0]=kpl[0]; pkl[1]=kpl[1];
    pvh[0]=vph[0]; pvh[1]=vph[1]; pvl[0]=vpl[0]; pvl[1]=vpl[1];
  }

  f32x4 co[4];
  #pragma unroll
  for (int n = 0; n < 4; ++n) co[n] = (f32x4)0.f;
  float mrun = -1e20f, lrun = 0.f;
  const int iq = qt*64 + w*16 + c;
  const int pbase = w*2048;

  for (int kt = kt0; ; ++kt) {
    // ---- S^T = K . Q^T ----
    f32x4 sc[4];
    #pragma unroll
    for (int f = 0; f < 4; ++f) sc[f] = (f32x4)0.f;
    #pragma unroll
    for (int ks = 0; ks < 2; ++ks) {
      #pragma unroll
      for (int f = 0; f < 4; ++f) {
        const int off = swz(f*16 + c, ks*32 + g*8);
        const bf16x8 ah = *(const bf16x8*)(Kh + off);
        const bf16x8 al = *(const bf16x8*)(Kl + off);
        sc[f] = __builtin_amdgcn_mfma_f32_16x16x32_bf16(ah, qbh[ks], sc[f], 0,0,0);
        sc[f] = __builtin_amdgcn_mfma_f32_16x16x32_bf16(al, qbh[ks], sc[f], 0,0,0);
        sc[f] = __builtin_amdgcn_mfma_f32_16x16x32_bf16(ah, qbl[ks], sc[f], 0,0,0);
      }
    }
    // ---- online softmax (lane owns q=c, 16 keys) ----
    float sv[4][4];
    float mt = -1e30f;
    #pragma unroll
    for (int f = 0; f < 4; ++f)
      #pragma unroll
      for (int r = 0; r < 4; ++r) {
        const int rel = kt*64 + f*16 + g*4 + r - iq;
        float s = fmaf(sc[f][r], 0.125f, slope*(float)rel);
        s = (rel > 0 || rel < -255) ? -1e30f : s;
        sv[f][r] = s;
        mt = fmaxf(mt, s);
      }
    mt = fmaxf(mt, __shfl_xor(mt, 16));
    mt = fmaxf(mt, __shfl_xor(mt, 32));
    const float mnew = fmaxf(mrun, mt);
    const float corr = __expf(mrun - mnew);
    mrun = mnew;
    float pw[4][4];
    float psum = 0.f;
    #pragma unroll
    for (int f = 0; f < 4; ++f)
      #pragma unroll
      for (int r = 0; r < 4; ++r) {
        const float p = __expf(sv[f][r] - mnew);
        pw[f][r] = p;
        psum += p;
      }
    psum += __shfl_xor(psum, 16);
    psum += __shfl_xor(psum, 32);
    lrun = lrun*corr + psum;
    // ---- P -> LDS hi/lo bf16 ----
    #pragma unroll
    for (int f = 0; f < 4; ++f) {
      const int off = swz(c, f*16 + g*4);
      uint2v ph2, pl2;
      ph2.x = pack_hi2(pw[f][0], pw[f][1]);
      ph2.y = pack_hi2(pw[f][2], pw[f][3]);
      pl2.x = pack_hi2(pw[f][0]-trunc16(pw[f][0]), pw[f][1]-trunc16(pw[f][1]));
      pl2.y = pack_hi2(pw[f][2]-trunc16(pw[f][2]), pw[f][3]-trunc16(pw[f][3]));
      *(uint2v*)(Ph + pbase + off) = ph2;
      *(uint2v*)(Pl + pbase + off) = pl2;
    }
    // ---- rescale O ----
    const float c0 = __shfl(corr, g*4+0);
    const float c1 = __shfl(corr, g*4+1);
    const float c2 = __shfl(corr, g*4+2);
    const float c3 = __shfl(corr, g*4+3);
    #pragma unroll
    for (int n = 0; n < 4; ++n) {
      co[n][0] *= c0; co[n][1] *= c1; co[n][2] *= c2; co[n][3] *= c3;
    }
    // ---- O += P . V ----
    #pragma unroll
    for (int ks = 0; ks < 2; ++ks) {
      const int poff = swz(c, ks*32 + g*8);
      const bf16x8 pah = *(const bf16x8*)(Ph + pbase + poff);
      const bf16x8 pal = *(const bf16x8*)(Pl + pbase + poff);
      #pragma unroll
      for (int n = 0; n < 4; ++n) {
        const int voff = swz(n*16 + c, ks*32 + g*8);
        const bf16x8 vbh = *(const bf16x8*)(Vh + voff);
        const bf16x8 vbl = *(const bf16x8*)(Vl + voff);
        co[n] = __builtin_amdgcn_mfma_f32_16x16x32_bf16(pah, vbh, co[n], 0,0,0);
        co[n] = __builtin_amdgcn_mfma_f32_16x16x32_bf16(pal, vbh, co[n], 0,0,0);
        co[n] = __builtin_amdgcn_mfma_f32_16x16x32_bf16(pah, vbl, co[n], 0,0,0);
      }
    }
    if (kt == ktN) break;
    __syncthreads();
    // write prefetched K/V(kt+1): pure copies
    {
      *(uint4v*)(Kh+swz(srow,scq))   = pkh[0]; *(uint4v*)(Kh+swz(srow,scq+8)) = pkh[1];
      *(uint4v*)(Kl+swz(srow,scq))   = pkl[0]; *(uint4v*)(Kl+swz(srow,scq+8)) = pkl[1];
      #pragma unroll
      for (int j = 0; j < 4; ++j) {
        const int d0 = vdb + 2*j, d1 = vdb + 8 + 2*j;
        unsigned wh = pvh[0][j], wl = pvl[0][j];
        *(ushort_t*)(Vh + swz(d0,   vkey)) = (ushort_t)(wh & 0xffffu);
        *(ushort_t*)(Vh + swz(d0+1, vkey)) = (ushort_t)(wh >> 16);
        *(ushort_t*)(Vl + swz(d0,   vkey)) = (ushort_t)(wl & 0xffffu);
        *(ushort_t*)(Vl + swz(d0+1, vkey)) = (ushort_t)(wl >> 16);
        wh = pvh[1][j]; wl = pvl[1][j];
        *(ushort_t*)(Vh + swz(d1,   vkey)) = (ushort_t)(wh & 0xffffu);
        *(ushort_t*)(Vh + swz(d1+1, vkey)) = (ushort_t)(wh >> 16);
        *(ushort_t*)(Vl + swz(d1,   vkey)) = (ushort_t)(wl & 0xffffu);
        *(ushort_t*)(Vl + swz(d1+1, vkey)) = (ushort_t)(wl >> 16);
      }
    }
    __syncthreads();
    if (kt + 1 < ktN) {
      const uint4v* kph = (const uint4v*)(kgh + (size_t)((kt+2)*64 + srow)*D_ + scq);
      const uint4v* kpl = (const uint4v*)(kgl + (size_t)((kt+2)*64 + srow)*D_ + scq);
      const uint4v* vph = (const uint4v*)(vgh + (size_t)((kt+2)*64 + vkey)*D_ + vdb);
      const uint4v* vpl = (const uint4v*)(vgl + (size_t)((kt+2)*64 + vkey)*D_ + vdb);
      pkh[0]=kph[0]; pkh[1]=kph[1]; pkl[0]=kpl[0]; pkl[1]=kpl[1];
      pvh[0]=vph[0]; pvh[1]=vph[1]; pvl[0]=vpl[0]; pvl[1]=vpl[1];
    }
  }

  // ---- epilogue: bf16 hi/lo out ----
  float linv[4];
  #pragma unroll
  for (int r = 0; r < 4; ++r) linv[r] = 1.f / __shfl(lrun, g*4+r);
  #pragma unroll
  for (int n = 0; n < 4; ++n)
    #pragma unroll
    for (int r = 0; r < 4; ++r) {
      const int qrow = qt*64 + w*16 + g*4 + r;
      const float val = co[n][r] * linv[r];
      const size_t idx = ((size_t)b*N_ + qrow)*C_ + h*64 + n*16 + c;
      outh[idx] = (ushort_t)(__float_as_uint(val) >> 16);
      outl[idx] = (ushort_t)(__float_as_uint(val - trunc16(val)) >> 16);
    }
}

// ===========================================================================
// FALLBACK PATH (validated R4 kernels, verbatim)
// ===========================================================================
template<int MODE>
__global__ __launch_bounds__(256, 2)
void gemm3_nt(const float* __restrict__ A, const float* __restrict__ Bw,
              const float* __restrict__ bias, float* __restrict__ Cd,
              int Ncols, int K)
{
  __shared__ char smem[65536];
  char* Ah = smem;          char* Al = smem + 16384;
  char* Bh = smem + 32768;  char* Bl = smem + 49152;
  const int t = threadIdx.x;
  const int lane = t & 63;
  const int w = t >> 6;
  const int wm = w >> 1, wn = w & 1;
  const int mb = blockIdx.x, nb = blockIdx.y;
  const int srow = t >> 1;
  const int skh  = (t & 1) * 32;
  const float* Ag = A  + (size_t)(mb*128 + srow)*K + skh;
  const float* Bg = Bw + (size_t)(nb*128 + srow)*K + skh;
  f32x4 acc[4][4];
  #pragma unroll
  for (int m = 0; m < 4; ++m)
    #pragma unroll
    for (int n = 0; n < 4; ++n) acc[m][n] = (f32x4)0.f;
  float4 fa[8], fb[8];
  {
    const float4* ap = (const float4*)Ag;
    const float4* bp = (const float4*)Bg;
    #pragma unroll
    for (int i = 0; i < 8; ++i) { fa[i] = ap[i]; fb[i] = bp[i]; }
  }
  const int fr = lane & 15;
  const int fg = lane >> 4;
  const int nkt = K / 64;
  for (int kt = 0; kt < nkt; ++kt) {
    __syncthreads();
    #pragma unroll
    for (int cc = 0; cc < 4; ++cc) {
      uint4v hi, lo;
      const int off = swz(srow, skh + cc*8);
      cvt8(fa[2*cc], fa[2*cc+1], hi, lo);
      *(uint4v*)(Ah + off) = hi;  *(uint4v*)(Al + off) = lo;
      cvt8(fb[2*cc], fb[2*cc+1], hi, lo);
      *(uint4v*)(Bh + off) = hi;  *(uint4v*)(Bl + off) = lo;
    }
    __syncthreads();
    if (kt + 1 < nkt) {
      const float4* ap = (const float4*)(Ag + (kt+1)*64);
      const float4* bp = (const float4*)(Bg + (kt+1)*64);
      #pragma unroll
      for (int i = 0; i < 8; ++i) { fa[i] = ap[i]; fb[i] = bp[i]; }
    }
    #pragma unroll
    for (int ks = 0; ks < 2; ++ks) {
      const int ke = ks*32 + fg*8;
      bf16x8 ah[4], al[4];
      #pragma unroll
      for (int m = 0; m < 4; ++m) {
        const int off = swz(wm*64 + m*16 + fr, ke);
        ah[m] = *(const bf16x8*)(Ah + off);
        al[m] = *(const bf16x8*)(Al + off);
      }
      #pragma unroll
      for (int n = 0; n < 4; ++n) {
        const int off = swz(wn*64 + n*16 + fr, ke);
        const bf16x8 bh = *(const bf16x8*)(Bh + off);
        const bf16x8 bl = *(const bf16x8*)(Bl + off);
        #pragma unroll
        for (int m = 0; m < 4; ++m) {
          acc[m][n] = __builtin_amdgcn_mfma_f32_16x16x32_bf16(ah[m], bh, acc[m][n], 0, 0, 0);
          acc[m][n] = __builtin_amdgcn_mfma_f32_16x16x32_bf16(al[m], bh, acc[m][n], 0, 0, 0);
          acc[m][n] = __builtin_amdgcn_mfma_f32_16x16x32_bf16(ah[m], bl, acc[m][n], 0, 0, 0);
        }
      }
    }
  }
  #pragma unroll
  for (int n = 0; n < 4; ++n) {
    const int col = nb*128 + wn*64 + n*16 + fr;
    const float bb = bias[col];
    int which = 0, hh = 0, dd = 0;
    if (MODE == 1) { which = col >> 10; hh = (col >> 6) & 15; dd = col & 63; }
    #pragma unroll
    for (int m = 0; m < 4; ++m) {
      const int row0 = mb*128 + wm*64 + m*16 + fg*4;
      #pragma unroll
      for (int j = 0; j < 4; ++j) {
        const int row = row0 + j;
        const float val = acc[m][n][j] + bb;
        if (MODE == 0) {
          Cd[(size_t)row*Ncols + col] = val;
        } else {
          const int b = row >> 11, i = row & 2047;
          Cd[(size_t)which*BHND + (((size_t)(b*H_ + hh))*N_ + i)*D_ + dd] = val;
        }
      }
    }
  }
}

__global__ __launch_bounds__(256, 2)
void attn_mfma(const float* __restrict__ qkv, float* __restrict__ attn_out)
{
  __shared__ char smem[65536];
  char* Qh = smem;
  char* Ql = smem + 8192;
  char* Kh = smem + 16384;
  char* Kl = smem + 24576;
  char* Vh = smem + 32768;
  char* Vl = smem + 40960;
  char* Ph = smem + 49152;
  char* Pl = smem + 57344;
  const int t = threadIdx.x;
  const int lane = t & 63;
  const int w = t >> 6;
  const int g = lane >> 4;
  const int c = lane & 15;
  const int qt = blockIdx.x & 31;
  const int bh = blockIdx.x >> 5;
  const int h = bh & 15;
  const int b = bh >> 4;
  const float* qg = qkv + (size_t)bh*N_*D_;
  const float* kg = qg + (size_t)BHND;
  const float* vg = kg + (size_t)BHND;
  const float slope = exp2f(-0.5f*(float)(h+1));
  const int kt0 = max(0, qt - 4);
  const int ktN = qt;
  const int srow = t >> 2;
  const int scq  = (t & 3) * 16;
  const int vkey = t & 63;
  const int vdb  = (t >> 6) * 16;
  {
    const float4* qp = (const float4*)(qg + (size_t)(qt*64 + srow)*D_ + scq);
    float4 q0=qp[0], q1=qp[1], q2=qp[2], q3=qp[3];
    const float4* kp = (const float4*)(kg + (size_t)(kt0*64 + srow)*D_ + scq);
    float4 k0=kp[0], k1=kp[1], k2=kp[2], k3=kp[3];
    const float4* vp = (const float4*)(vg + (size_t)(kt0*64 + vkey)*D_ + vdb);
    float4 v0=vp[0], v1=vp[1], v2=vp[2], v3=vp[3];
    uint4v hi, lo;
    cvt8(q0,q1,hi,lo); *(uint4v*)(Qh+swz(srow,scq  ))=hi; *(uint4v*)(Ql+swz(srow,scq  ))=lo;
    cvt8(q2,q3,hi,lo); *(uint4v*)(Qh+swz(srow,scq+8))=hi; *(uint4v*)(Ql+swz(srow,scq+8))=lo;
    cvt8(k0,k1,hi,lo); *(uint4v*)(Kh+swz(srow,scq  ))=hi; *(uint4v*)(Kl+swz(srow,scq  ))=lo;
    cvt8(k2,k3,hi,lo); *(uint4v*)(Kh+swz(srow,scq+8))=hi; *(uint4v*)(Kl+swz(srow,scq+8))=lo;
    const float vv[16] = {v0.x,v0.y,v0.z,v0.w, v1.x,v1.y,v1.z,v1.w,
                          v2.x,v2.y,v2.z,v2.w, v3.x,v3.y,v3.z,v3.w};
    #pragma unroll
    for (int d16 = 0; d16 < 16; ++d16) {
      const int d  = vdb + d16;
      const int off = swz(d, vkey);
      const unsigned xu = __float_as_uint(vv[d16]);
      *(unsigned short*)(Vh + off) = (unsigned short)(xu >> 16);
      const float xt = __uint_as_float(xu & 0xFFFF0000u);
      *(unsigned short*)(Vl + off) = (unsigned short)(__float_as_uint(vv[d16] - xt) >> 16);
    }
  }
  __syncthreads();
  bf16x8 qbh[2], qbl[2];
  #pragma unroll
  for (int ks = 0; ks < 2; ++ks) {
    const int off = swz(w*16 + c, ks*32 + g*8);
    qbh[ks] = *(const bf16x8*)(Qh + off);
    qbl[ks] = *(const bf16x8*)(Ql + off);
  }
  float4 pk[4], pvv[4];
  if (kt0 < ktN) {
    const float4* kp = (const float4*)(kg + (size_t)((kt0+1)*64 + srow)*D_ + scq);
    const float4* vp = (const float4*)(vg + (size_t)((kt0+1)*64 + vkey)*D_ + vdb);
    #pragma unroll
    for (int i = 0; i < 4; ++i) { pk[i] = kp[i]; pvv[i] = vp[i]; }
  }
  f32x4 co[4];
  #pragma unroll
  for (int n = 0; n < 4; ++n) co[n] = (f32x4)0.f;
  float mrun = -1e20f, lrun = 0.f;
  const int iq = qt*64 + w*16 + c;
  const int pbase = w*2048;
  for (int kt = kt0; ; ++kt) {
    f32x4 sc[4];
    #pragma unroll
    for (int f = 0; f < 4; ++f) sc[f] = (f32x4)0.f;
    #pragma unroll
    for (int ks = 0; ks < 2; ++ks) {
      #pragma unroll
      for (int f = 0; f < 4; ++f) {
        const int off = swz(f*16 + c, ks*32 + g*8);
        const bf16x8 ah = *(const bf16x8*)(Kh + off);
        const bf16x8 al = *(const bf16x8*)(Kl + off);
        sc[f] = __builtin_amdgcn_mfma_f32_16x16x32_bf16(ah, qbh[ks], sc[f], 0,0,0);
        sc[f] = __builtin_amdgcn_mfma_f32_16x16x32_bf16(al, qbh[ks], sc[f], 0,0,0);
        sc[f] = __builtin_amdgcn_mfma_f32_16x16x32_bf16(ah, qbl[ks], sc[f], 0,0,0);
      }
    }
    float sv[4][4];
    float mt = -1e30f;
    #pragma unroll
    for (int f = 0; f < 4; ++f)
      #pragma unroll
      for (int r = 0; r < 4; ++r) {
        const int rel = kt*64 + f*16 + g*4 + r - iq;
        float s = fmaf(sc[f][r], 0.125f, slope*(float)rel);
        s = (rel > 0 || rel < -255) ? -1e30f : s;
        sv[f][r] = s;
        mt = fmaxf(mt, s);
      }
    mt = fmaxf(mt, __shfl_xor(mt, 16));
    mt = fmaxf(mt, __shfl_xor(mt, 32));
    const float mnew = fmaxf(mrun, mt);
    const float corr = __expf(mrun - mnew);
    mrun = mnew;
    float pw[4][4];
    float psum = 0.f;
    #pragma unroll
    for (int f = 0; f < 4; ++f)
      #pragma unroll
      for (int r = 0; r < 4; ++r) {
        const float p = __expf(sv[f][r] - mnew);
        pw[f][r] = p;
        psum += p;
      }
    psum += __shfl_xor(psum, 16);
    psum += __shfl_xor(psum, 32);
    lrun = lrun*corr + psum;
    #pragma unroll
    for (int f = 0; f < 4; ++f) {
      const int off = swz(c, f*16 + g*4);
      uint2v ph2, pl2;
      ph2.x = pack_hi2(pw[f][0], pw[f][1]);
      ph2.y = pack_hi2(pw[f][2], pw[f][3]);
      pl2.x = pack_hi2(pw[f][0]-trunc16(pw[f][0]), pw[f][1]-trunc16(pw[f][1]));
      pl2.y = pack_hi2(pw[f][2]-trunc16(pw[f][2]), pw[f][3]-trunc16(pw[f][3]));
      *(uint2v*)(Ph + pbase + off) = ph2;
      *(uint2v*)(Pl + pbase + off) = pl2;
    }
    const float c0 = __shfl(corr, g*4+0);
    const float c1 = __shfl(corr, g*4+1);
    const float c2 = __shfl(corr, g*4+2);
    const float c3 = __shfl(corr, g*4+3);
    #pragma unroll
    for (int n = 0; n < 4; ++n) {
      co[n][0] *= c0; co[n][1] *= c1; co[n][2] *= c2; co[n][3] *= c3;
    }
    #pragma unroll
    for (int ks = 0; ks < 2; ++ks) {
      const int poff = swz(c, ks*32 + g*8);
      const bf16x8 pah = *(const bf16x8*)(Ph + pbase + poff);
      const bf16x8 pal = *(const bf16x8*)(Pl + pbase + poff);
      #pragma unroll
      for (int n = 0; n < 4; ++n) {
        const int voff = swz(n*16 + c, ks*32 + g*8);
        const bf16x8 vbh = *(const bf16x8*)(Vh + voff);
        const bf16x8 vbl = *(const bf16x8*)(Vl + voff);
        co[n] = __builtin_amdgcn_mfma_f32_16x16x32_bf16(pah, vbh, co[n], 0,0,0);
        co[n] = __builtin_amdgcn_mfma_f32_16x16x32_bf16(pal, vbh, co[n], 0,0,0);
        co[n] = __builtin_amdgcn_mfma_f32_16x16x32_bf16(pah, vbl, co[n], 0,0,0);
      }
    }
    if (kt == ktN) break;
    __syncthreads();
    {
      uint4v hi, lo;
      cvt8(pk[0], pk[1], hi, lo);
      *(uint4v*)(Kh+swz(srow,scq  ))=hi; *(uint4v*)(Kl+swz(srow,scq  ))=lo;
      cvt8(pk[2], pk[3], hi, lo);
      *(uint4v*)(Kh+swz(srow,scq+8))=hi; *(uint4v*)(Kl+swz(srow,scq+8))=lo;
      const float vv[16] = {pvv[0].x,pvv[0].y,pvv[0].z,pvv[0].w,
                            pvv[1].x,pvv[1].y,pvv[1].z,pvv[1].w,
                            pvv[2].x,pvv[2].y,pvv[2].z,pvv[2].w,
                            pvv[3].x,pvv[3].y,pvv[3].z,pvv[3].w};
      #pragma unroll
      for (int d16 = 0; d16 < 16; ++d16) {
        const int d  = vdb + d16;
        const int off = swz(d, vkey);
        const unsigned xu = __float_as_uint(vv[d16]);
        *(unsigned short*)(Vh + off) = (unsigned short)(xu >> 16);
        const float xt = __uint_as_float(xu & 0xFFFF0000u);
        *(unsigned short*)(Vl + off) = (unsigned short)(__float_as_uint(vv[d16] - xt) >> 16);
      }
    }
    __syncthreads();
    if (kt + 1 < ktN) {
      const float4* kp = (const float4*)(kg + (size_t)((kt+2)*64 + srow)*D_ + scq);
      const float4* vp = (const float4*)(vg + (size_t)((kt+2)*64 + vkey)*D_ + vdb);
      #pragma unroll
      for (int i = 0; i < 4; ++i) { pk[i] = kp[i]; pvv[i] = vp[i]; }
    }
  }
  float linv[4];
  #pragma unroll
  for (int r = 0; r < 4; ++r) linv[r] = 1.f / __shfl(lrun, g*4+r);
  #pragma unroll
  for (int n = 0; n < 4; ++n)
    #pragma unroll
    for (int r = 0; r < 4; ++r) {
      const int qrow = qt*64 + w*16 + g*4 + r;
      attn_out[((size_t)b*N_ + qrow)*C_ + h*64 + n*16 + c] = co[n][r] * linv[r];
    }
}

// ===========================================================================
// Launcher. New-path ws layout (ushorts):
//   qkvh[3*BHND] qkvl[3*BHND] attnh[BNC] attnl[BNC] xh[BNC] xl[BNC]
//   qwh[3C*C] qwl[3C*C] pwh[C*C] pwl[C*C]      total = 100,663,296 bytes
// Fallback ws layout (floats): qkv[3*BHND], attn[BNC]  (67.1 MB, validated)
// ===========================================================================
extern "C" void kernel_launch(void* const* d_in, const int* in_sizes, int n_in,
                              void* d_out, int out_size, void* d_ws, size_t ws_size,
                              hipStream_t stream)
{
  const float* x      = (const float*)d_in[0];
  const float* qkv_w  = (const float*)d_in[1];
  const float* qkv_b  = (const float*)d_in[2];
  const float* proj_w = (const float*)d_in[3];
  const float* proj_b = (const float*)d_in[4];
  float* out = (float*)d_out;

  const size_t NEED = 100663296;
  if (ws_size >= NEED) {
    ushort_t* W     = (ushort_t*)d_ws;
    ushort_t* qkvh  = W;
    ushort_t* qkvl  = qkvh + (size_t)3*BHND;
    ushort_t* attnh = qkvl + (size_t)3*BHND;
    ushort_t* attnl = attnh + (size_t)BNC;
    ushort_t* xh    = attnl + (size_t)BNC;
    ushort_t* xl    = xh + (size_t)BNC;
    ushort_t* qwh   = xl + (size_t)BNC;
    ushort_t* qwl   = qwh + (size_t)3*C_*C_;
    ushort_t* pwh   = qwl + (size_t)3*C_*C_;
    ushort_t* pwl   = pwh + (size_t)C_*C_;

    auto grid_for = [](int n4) { int g = (n4 + 255) / 256; return g > 2048 ? 2048 : g; };
    cvt_split<<<grid_for(BNC/4), 256, 0, stream>>>(x, xh, xl, BNC/4);
    cvt_split<<<grid_for(3*C_*C_/4), 256, 0, stream>>>(qkv_w, qwh, qwl, 3*C_*C_/4);
    cvt_split<<<grid_for(C_*C_/4), 256, 0, stream>>>(proj_w, pwh, pwl, C_*C_/4);
    // QKV: [4096,1024]x[1024,3072]^T -> bf16 hi/lo scatter [3][B*H][N][D]
    gemm_b3<1><<<dim3(32, 24), 256, 0, stream>>>(xh, xl, qwh, qwl, qkv_b,
                                                 nullptr, qkvh, qkvl, 3*C_, C_);
    // MFMA flash attention -> bf16 hi/lo [B,N,C]
    attn_b3<<<dim3(1024), 256, 0, stream>>>(qkvh, qkvl, attnh, attnl);
    // Proj: [4096,1024]x[1024,1024]^T + bias -> fp32 d_out
    gemm_b3<0><<<dim3(32, 8), 256, 0, stream>>>(attnh, attnl, pwh, pwl, proj_b,
                                                out, nullptr, nullptr, C_, C_);
  } else {
    // validated R4 path
    float* qkv  = (float*)d_ws;
    float* attn = qkv + (size_t)3*BHND;
    gemm3_nt<1><<<dim3(32, 24), 256, 0, stream>>>(x, qkv_w, qkv_b, qkv, 3*C_, C_);
    attn_mfma<<<dim3(1024), 256, 0, stream>>>(qkv, attn);
    gemm3_nt<0><<<dim3(32, 8), 256, 0, stream>>>(attn, proj_w, proj_b, out, C_, C_);
  }
}